// Round 2
// baseline (219.219 us; speedup 1.0000x reference)
//
#include <hip/hip_runtime.h>
#include <hip/hip_bf16.h>

#define B_ 4
#define C_IN 128
#define C_OUT 256
#define N_IN 40962
#define N_OUT 10242
#define EPS_ 1e-5f

typedef __attribute__((ext_vector_type(8))) short bf16x8;
typedef __attribute__((ext_vector_type(4))) float f32x4;

__device__ __forceinline__ float bf2f(unsigned short u) {
    union { unsigned int i; float f; } c;
    c.i = ((unsigned int)u) << 16;
    return c.f;
}
__device__ __forceinline__ unsigned short f2bf(float f) {
    union { float f; unsigned int i; } c;
    c.f = f;
    unsigned int r = c.i + 0x7FFFu + ((c.i >> 16) & 1u);  // RNE
    return (unsigned short)(r >> 16);
}

// ---------------------------------------------------------------------------
// K0: W f32 -> bf16 (done once; kills per-block repack VALU and halves traffic)
// ---------------------------------------------------------------------------
__global__ __launch_bounds__(256) void k_wconv(const float* __restrict__ W,
                                               unsigned short* __restrict__ Wb) {
    int i = blockIdx.x * 256 + threadIdx.x;  // grid exactly covers 256*128
    Wb[i] = f2bf(W[i]);
}

// ---------------------------------------------------------------------------
// K1: transpose x[b][k][i] (f32) -> xT[b][i][k] (bf16), coalesced both sides
// ---------------------------------------------------------------------------
#define IBLK 64
#define NB_I ((N_IN + IBLK - 1) / IBLK)  // 641

__global__ __launch_bounds__(256) void k_transpose(const float* __restrict__ x,
                                                   unsigned short* __restrict__ xT) {
    __shared__ float tile[IBLK][C_IN + 1];
    int b  = blockIdx.x / NB_I;
    int ib = blockIdx.x % NB_I;
    int i0 = ib * IBLK;
    int t = threadIdx.x;
    int lane = t & 63;
    int q = t >> 6;  // 0..3

    const float* xb = x + (size_t)b * C_IN * N_IN;
    int i = i0 + lane;
    if (i < N_IN) {
#pragma unroll
        for (int p = 0; p < 32; p++) {
            int k = p * 4 + q;
            tile[lane][k] = xb[(size_t)k * N_IN + i];
        }
    }
    __syncthreads();

    unsigned short* xTb = xT + (size_t)b * N_IN * C_IN;
#pragma unroll
    for (int p = 0; p < 16; p++) {
        int il = p * 4 + q;
        int gi = i0 + il;
        if (gi < N_IN) {
            int k2 = lane * 2;
            float a = tile[il][k2];
            float c = tile[il][k2 + 1];
            unsigned int pk = (unsigned int)f2bf(a) | ((unsigned int)f2bf(c) << 16);
            *reinterpret_cast<unsigned int*>(xTb + (size_t)gi * C_IN + k2) = pk;
        }
    }
}

// ---------------------------------------------------------------------------
// K2: gather-mean: g[b][n][k] = mean_j xT[b][idx[7n+j]][k]  (bf16 out)
// 16 threads per n (each owns a 16B k-chunk); each row read is 256B coalesced.
// ---------------------------------------------------------------------------
#define GNB 16
#define NB_G ((N_OUT + GNB - 1) / GNB)  // 641

__global__ __launch_bounds__(256) void k_gather(const unsigned short* __restrict__ xT,
                                                const int* __restrict__ idx,
                                                unsigned short* __restrict__ g) {
    int b  = blockIdx.x / NB_G;
    int nb = blockIdx.x % NB_G;
    int t = threadIdx.x;
    int n = nb * GNB + (t >> 4);
    int c = t & 15;
    if (n >= N_OUT) return;

    const unsigned short* xTb = xT + (size_t)b * N_IN * C_IN;
    const int* ip = idx + 7 * n;
    float s[8];
#pragma unroll
    for (int e = 0; e < 8; e++) s[e] = 0.f;
#pragma unroll
    for (int j = 0; j < 7; j++) {
        int id = ip[j];
        bf16x8 v = *reinterpret_cast<const bf16x8*>(xTb + (size_t)id * C_IN + c * 8);
#pragma unroll
        for (int e = 0; e < 8; e++) s[e] += bf2f((unsigned short)v[e]);
    }
    const float inv7 = 1.0f / 7.0f;
    bf16x8 r;
#pragma unroll
    for (int e = 0; e < 8; e++) r[e] = (short)f2bf(s[e] * inv7);
    *reinterpret_cast<bf16x8*>(g + ((size_t)b * N_OUT + n) * C_IN + c * 8) = r;
}

// ---------------------------------------------------------------------------
// GEMM core (shared by stats + final): 32-n tile per block, wave w owns 64 ch.
// ---------------------------------------------------------------------------
#define NT2 32
#define NB_N2 ((N_OUT + NT2 - 1) / NT2)  // 321

// K3: GEMM -> per-channel partial sums only (no y write)
__global__ __launch_bounds__(256) void k_stats_gemm(const unsigned short* __restrict__ g,
                                                    const unsigned short* __restrict__ Wb,
                                                    const float* __restrict__ bias,
                                                    float* __restrict__ sums) {
    int b  = blockIdx.x / NB_N2;
    int nb = blockIdx.x % NB_N2;
    int n0 = nb * NT2;
    int t = threadIdx.x;
    int w = t >> 6, l = t & 63, lr = l & 15, lg = l >> 4;
    int wbase = w * 64;

    bf16x8 afrag[4][4];
#pragma unroll
    for (int mt = 0; mt < 4; mt++)
#pragma unroll
        for (int ks = 0; ks < 4; ks++)
            afrag[mt][ks] = *reinterpret_cast<const bf16x8*>(
                Wb + (size_t)(wbase + mt * 16 + lr) * C_IN + ks * 32 + lg * 8);

    f32x4 acc[4][2];
#pragma unroll
    for (int mt = 0; mt < 4; mt++)
#pragma unroll
        for (int nt = 0; nt < 2; nt++) acc[mt][nt] = (f32x4)(0.0f);

    const unsigned short* gb = g + (size_t)b * N_OUT * C_IN;
#pragma unroll
    for (int nt = 0; nt < 2; nt++) {
        int n = n0 + nt * 16 + lr;
        const unsigned short* gr = gb + (size_t)((n < N_OUT) ? n : 0) * C_IN;
#pragma unroll
        for (int ks = 0; ks < 4; ks++) {
            bf16x8 bfr = *reinterpret_cast<const bf16x8*>(gr + ks * 32 + lg * 8);
#pragma unroll
            for (int mt = 0; mt < 4; mt++)
                acc[mt][nt] = __builtin_amdgcn_mfma_f32_16x16x32_bf16(afrag[mt][ks], bfr,
                                                                     acc[mt][nt], 0, 0, 0);
        }
    }

    float ps1[16], ps2[16];
#pragma unroll
    for (int m = 0; m < 16; m++) { ps1[m] = 0.f; ps2[m] = 0.f; }
#pragma unroll
    for (int mt = 0; mt < 4; mt++) {
#pragma unroll
        for (int j = 0; j < 4; j++) {
            int o = wbase + mt * 16 + lg * 4 + j;
            float bv = bias[o];
#pragma unroll
            for (int nt = 0; nt < 2; nt++) {
                int n = n0 + nt * 16 + lr;
                if (n < N_OUT) {
                    float v = acc[mt][nt][j] + bv;
                    ps1[mt * 4 + j] += v;
                    ps2[mt * 4 + j] += v * v;
                }
            }
        }
    }
#pragma unroll
    for (int m = 0; m < 16; m++) {
        float a = ps1[m], c = ps2[m];
#pragma unroll
        for (int d = 1; d < 16; d <<= 1) {
            a += __shfl_xor(a, d, 64);
            c += __shfl_xor(c, d, 64);
        }
        if (lr == 0) {
            int mt = m >> 2, j = m & 3;
            int o = wbase + mt * 16 + lg * 4 + j;
            atomicAdd(&sums[o], a);
            atomicAdd(&sums[C_OUT + o], c);
        }
    }
}

// K4: finalize -> scale/shift (bias folded in)
__global__ void k_finalize(const float* __restrict__ sums, const float* __restrict__ bias,
                           const float* __restrict__ gamma, const float* __restrict__ beta,
                           float* __restrict__ ss) {
    int o = threadIdx.x;
    const float cnt = (float)(B_ * N_OUT);
    float mean = sums[o] / cnt;
    float var = sums[C_OUT + o] / cnt - mean * mean;
    float a = gamma[o] * rsqrtf(var + EPS_);
    ss[o] = a;
    ss[C_OUT + o] = a * bias[o] + beta[o] - a * mean;
}

// K5: GEMM again + normalize + write out
__global__ __launch_bounds__(256) void k_final_gemm(const unsigned short* __restrict__ g,
                                                    const unsigned short* __restrict__ Wb,
                                                    const float* __restrict__ ss,
                                                    float* __restrict__ out) {
    int b  = blockIdx.x / NB_N2;
    int nb = blockIdx.x % NB_N2;
    int n0 = nb * NT2;
    int t = threadIdx.x;
    int w = t >> 6, l = t & 63, lr = l & 15, lg = l >> 4;
    int wbase = w * 64;

    bf16x8 afrag[4][4];
#pragma unroll
    for (int mt = 0; mt < 4; mt++)
#pragma unroll
        for (int ks = 0; ks < 4; ks++)
            afrag[mt][ks] = *reinterpret_cast<const bf16x8*>(
                Wb + (size_t)(wbase + mt * 16 + lr) * C_IN + ks * 32 + lg * 8);

    f32x4 acc[4][2];
#pragma unroll
    for (int mt = 0; mt < 4; mt++)
#pragma unroll
        for (int nt = 0; nt < 2; nt++) acc[mt][nt] = (f32x4)(0.0f);

    const unsigned short* gb = g + (size_t)b * N_OUT * C_IN;
#pragma unroll
    for (int nt = 0; nt < 2; nt++) {
        int n = n0 + nt * 16 + lr;
        const unsigned short* gr = gb + (size_t)((n < N_OUT) ? n : 0) * C_IN;
#pragma unroll
        for (int ks = 0; ks < 4; ks++) {
            bf16x8 bfr = *reinterpret_cast<const bf16x8*>(gr + ks * 32 + lg * 8);
#pragma unroll
            for (int mt = 0; mt < 4; mt++)
                acc[mt][nt] = __builtin_amdgcn_mfma_f32_16x16x32_bf16(afrag[mt][ks], bfr,
                                                                     acc[mt][nt], 0, 0, 0);
        }
    }

    float* ob = out + (size_t)b * C_OUT * N_OUT;
#pragma unroll
    for (int mt = 0; mt < 4; mt++) {
#pragma unroll
        for (int j = 0; j < 4; j++) {
            int o = wbase + mt * 16 + lg * 4 + j;
            float a = ss[o];
            float sh = ss[C_OUT + o];
#pragma unroll
            for (int nt = 0; nt < 2; nt++) {
                int n = n0 + nt * 16 + lr;
                if (n < N_OUT) ob[(size_t)o * N_OUT + n] = a * acc[mt][nt][j] + sh;
            }
        }
    }
}

// ---------------------------------------------------------------------------
extern "C" void kernel_launch(void* const* d_in, const int* in_sizes, int n_in,
                              void* d_out, int out_size, void* d_ws, size_t ws_size,
                              hipStream_t stream) {
    const float* x     = (const float*)d_in[0];
    const int*   idx   = (const int*)d_in[1];
    const float* W     = (const float*)d_in[2];
    const float* bias  = (const float*)d_in[3];
    const float* gamma = (const float*)d_in[4];
    const float* beta  = (const float*)d_in[5];
    float* out = (float*)d_out;

    const size_t xt_bytes = (size_t)B_ * N_IN * C_IN * sizeof(unsigned short);   // 41,945,088
    const size_t g_bytes  = (size_t)B_ * N_OUT * C_IN * sizeof(unsigned short);  // 10,487,808
    unsigned short* xT = (unsigned short*)d_ws;
    unsigned short* gg = (unsigned short*)((char*)d_ws + xt_bytes);
    unsigned short* Wb = (unsigned short*)((char*)d_ws + xt_bytes + g_bytes);
    float* sums = (float*)((char*)d_ws + xt_bytes + g_bytes + (size_t)C_OUT * C_IN * 2);
    float* ss   = sums + 2 * C_OUT;

    hipMemsetAsync(sums, 0, 2 * C_OUT * sizeof(float), stream);
    k_wconv<<<(C_OUT * C_IN) / 256, 256, 0, stream>>>(W, Wb);
    k_transpose<<<B_ * NB_I, 256, 0, stream>>>(x, xT);
    k_gather<<<B_ * NB_G, 256, 0, stream>>>(xT, idx, gg);
    k_stats_gemm<<<B_ * NB_N2, 256, 0, stream>>>(gg, Wb, bias, sums);
    k_finalize<<<1, C_OUT, 0, stream>>>(sums, bias, gamma, beta, ss);
    k_final_gemm<<<B_ * NB_N2, 256, 0, stream>>>(gg, Wb, ss, out);
}

// Round 3
// 109.234 us; speedup vs baseline: 2.0069x; 2.0069x over previous
//
#include <hip/hip_runtime.h>
#include <hip/hip_bf16.h>

#define B_ 4
#define C_IN 128
#define C_OUT 256
#define N_IN 40962
#define N_OUT 10242
#define EPS_ 1e-5f

typedef __attribute__((ext_vector_type(8))) short bf16x8;
typedef __attribute__((ext_vector_type(4))) float f32x4;

__device__ __forceinline__ float bf2f(unsigned short u) {
    union { unsigned int i; float f; } c;
    c.i = ((unsigned int)u) << 16;
    return c.f;
}
__device__ __forceinline__ unsigned short f2bf(float f) {
    union { float f; unsigned int i; } c;
    c.f = f;
    unsigned int r = c.i + 0x7FFFu + ((c.i >> 16) & 1u);  // RNE
    return (unsigned short)(r >> 16);
}

// ---------------------------------------------------------------------------
// K0: W f32 -> bf16
// ---------------------------------------------------------------------------
__global__ __launch_bounds__(256) void k_wconv(const float* __restrict__ W,
                                               unsigned short* __restrict__ Wb) {
    int i = blockIdx.x * 256 + threadIdx.x;
    Wb[i] = f2bf(W[i]);
}

// ---------------------------------------------------------------------------
// K1: transpose x[b][k][i] (f32) -> xT[b][i][k] (bf16)
// ---------------------------------------------------------------------------
#define IBLK 64
#define NB_I ((N_IN + IBLK - 1) / IBLK)  // 641

__global__ __launch_bounds__(256) void k_transpose(const float* __restrict__ x,
                                                   unsigned short* __restrict__ xT) {
    __shared__ float tile[IBLK][C_IN + 1];
    int b  = blockIdx.x / NB_I;
    int ib = blockIdx.x % NB_I;
    int i0 = ib * IBLK;
    int t = threadIdx.x;
    int lane = t & 63;
    int q = t >> 6;

    const float* xb = x + (size_t)b * C_IN * N_IN;
    int i = i0 + lane;
    if (i < N_IN) {
#pragma unroll
        for (int p = 0; p < 32; p++) {
            int k = p * 4 + q;
            tile[lane][k] = xb[(size_t)k * N_IN + i];
        }
    }
    __syncthreads();

    unsigned short* xTb = xT + (size_t)b * N_IN * C_IN;
#pragma unroll
    for (int p = 0; p < 16; p++) {
        int il = p * 4 + q;
        int gi = i0 + il;
        if (gi < N_IN) {
            int k2 = lane * 2;
            float a = tile[il][k2];
            float c = tile[il][k2 + 1];
            unsigned int pk = (unsigned int)f2bf(a) | ((unsigned int)f2bf(c) << 16);
            *reinterpret_cast<unsigned int*>(xTb + (size_t)gi * C_IN + k2) = pk;
        }
    }
}

// ---------------------------------------------------------------------------
// K2: gather-mean: g[b][n][k] = mean_j xT[b][idx[7n+j]][k]  (bf16 out)
// ---------------------------------------------------------------------------
#define GNB 16
#define NB_G ((N_OUT + GNB - 1) / GNB)  // 641

__global__ __launch_bounds__(256) void k_gather(const unsigned short* __restrict__ xT,
                                                const int* __restrict__ idx,
                                                unsigned short* __restrict__ g) {
    int b  = blockIdx.x / NB_G;
    int nb = blockIdx.x % NB_G;
    int t = threadIdx.x;
    int n = nb * GNB + (t >> 4);
    int c = t & 15;
    if (n >= N_OUT) return;

    const unsigned short* xTb = xT + (size_t)b * N_IN * C_IN;
    const int* ip = idx + 7 * n;
    float s[8];
#pragma unroll
    for (int e = 0; e < 8; e++) s[e] = 0.f;
#pragma unroll
    for (int j = 0; j < 7; j++) {
        int id = ip[j];
        bf16x8 v = *reinterpret_cast<const bf16x8*>(xTb + (size_t)id * C_IN + c * 8);
#pragma unroll
        for (int e = 0; e < 8; e++) s[e] += bf2f((unsigned short)v[e]);
    }
    const float inv7 = 1.0f / 7.0f;
    bf16x8 r;
#pragma unroll
    for (int e = 0; e < 8; e++) r[e] = (short)f2bf(s[e] * inv7);
    *reinterpret_cast<bf16x8*>(g + ((size_t)b * N_OUT + n) * C_IN + c * 8) = r;
}

// ---------------------------------------------------------------------------
// GEMM tiling shared constants
// ---------------------------------------------------------------------------
#define NT2 32
#define NB_N2 ((N_OUT + NT2 - 1) / NT2)  // 321
#define NBLK_STATS (B_ * NB_N2)          // 1284

// K3: GEMM -> per-block per-channel partials (NO atomics)
__global__ __launch_bounds__(256) void k_stats_gemm(const unsigned short* __restrict__ g,
                                                    const unsigned short* __restrict__ Wb,
                                                    const float* __restrict__ bias,
                                                    float* __restrict__ psum) {
    int bid = blockIdx.x;
    int b  = bid / NB_N2;
    int nb = bid % NB_N2;
    int n0 = nb * NT2;
    int t = threadIdx.x;
    int w = t >> 6, l = t & 63, lr = l & 15, lg = l >> 4;
    int wbase = w * 64;

    bf16x8 afrag[4][4];
#pragma unroll
    for (int mt = 0; mt < 4; mt++)
#pragma unroll
        for (int ks = 0; ks < 4; ks++)
            afrag[mt][ks] = *reinterpret_cast<const bf16x8*>(
                Wb + (size_t)(wbase + mt * 16 + lr) * C_IN + ks * 32 + lg * 8);

    f32x4 acc[4][2];
#pragma unroll
    for (int mt = 0; mt < 4; mt++)
#pragma unroll
        for (int nt = 0; nt < 2; nt++) acc[mt][nt] = (f32x4)(0.0f);

    const unsigned short* gb = g + (size_t)b * N_OUT * C_IN;
#pragma unroll
    for (int nt = 0; nt < 2; nt++) {
        int n = n0 + nt * 16 + lr;
        const unsigned short* gr = gb + (size_t)((n < N_OUT) ? n : 0) * C_IN;
#pragma unroll
        for (int ks = 0; ks < 4; ks++) {
            bf16x8 bfr = *reinterpret_cast<const bf16x8*>(gr + ks * 32 + lg * 8);
#pragma unroll
            for (int mt = 0; mt < 4; mt++)
                acc[mt][nt] = __builtin_amdgcn_mfma_f32_16x16x32_bf16(afrag[mt][ks], bfr,
                                                                     acc[mt][nt], 0, 0, 0);
        }
    }

    float ps1[16], ps2[16];
#pragma unroll
    for (int m = 0; m < 16; m++) { ps1[m] = 0.f; ps2[m] = 0.f; }
#pragma unroll
    for (int mt = 0; mt < 4; mt++) {
#pragma unroll
        for (int j = 0; j < 4; j++) {
            int o = wbase + mt * 16 + lg * 4 + j;
            float bv = bias[o];
#pragma unroll
            for (int nt = 0; nt < 2; nt++) {
                int n = n0 + nt * 16 + lr;
                if (n < N_OUT) {
                    float v = acc[mt][nt][j] + bv;
                    ps1[mt * 4 + j] += v;
                    ps2[mt * 4 + j] += v * v;
                }
            }
        }
    }

    __shared__ float red[2][C_OUT];
#pragma unroll
    for (int m = 0; m < 16; m++) {
        float a = ps1[m], c = ps2[m];
#pragma unroll
        for (int d = 1; d < 16; d <<= 1) {
            a += __shfl_xor(a, d, 64);
            c += __shfl_xor(c, d, 64);
        }
        if (lr == 0) {
            int mt = m >> 2, j = m & 3;
            int o = wbase + mt * 16 + lg * 4 + j;
            red[0][o] = a;
            red[1][o] = c;
        }
    }
    __syncthreads();
    float* pb = psum + (size_t)bid * 2 * C_OUT;
    pb[t] = red[0][t];
    pb[C_OUT + t] = red[1][t];
}

// K4a: tree reduce psum[1284][512] -> psum2[32][512]
#define RED_BLKS 32
__global__ __launch_bounds__(256) void k_reduce(const float* __restrict__ psum,
                                                float* __restrict__ psum2) {
    int r = blockIdx.x;
    int t = threadIdx.x;
    float a = 0.f, c = 0.f;
    for (int i = r; i < NBLK_STATS; i += RED_BLKS) {
        const float* pb = psum + (size_t)i * 2 * C_OUT;
        a += pb[t];
        c += pb[C_OUT + t];
    }
    float* qb = psum2 + (size_t)r * 2 * C_OUT;
    qb[t] = a;
    qb[C_OUT + t] = c;
}

// K4b: finalize -> scale/shift (bias folded in)
__global__ void k_finalize(const float* __restrict__ psum2, const float* __restrict__ bias,
                           const float* __restrict__ gamma, const float* __restrict__ beta,
                           float* __restrict__ ss) {
    int o = threadIdx.x;
    float s1 = 0.f, s2 = 0.f;
#pragma unroll 4
    for (int r = 0; r < RED_BLKS; r++) {
        s1 += psum2[(size_t)r * 2 * C_OUT + o];
        s2 += psum2[(size_t)r * 2 * C_OUT + C_OUT + o];
    }
    const float cnt = (float)(B_ * N_OUT);
    float mean = s1 / cnt;
    float var = s2 / cnt - mean * mean;
    float a = gamma[o] * rsqrtf(var + EPS_);
    ss[o] = a;
    ss[C_OUT + o] = a * bias[o] + beta[o] - a * mean;
}

// K5: GEMM again + normalize + write out
__global__ __launch_bounds__(256) void k_final_gemm(const unsigned short* __restrict__ g,
                                                    const unsigned short* __restrict__ Wb,
                                                    const float* __restrict__ ss,
                                                    float* __restrict__ out) {
    int b  = blockIdx.x / NB_N2;
    int nb = blockIdx.x % NB_N2;
    int n0 = nb * NT2;
    int t = threadIdx.x;
    int w = t >> 6, l = t & 63, lr = l & 15, lg = l >> 4;
    int wbase = w * 64;

    bf16x8 afrag[4][4];
#pragma unroll
    for (int mt = 0; mt < 4; mt++)
#pragma unroll
        for (int ks = 0; ks < 4; ks++)
            afrag[mt][ks] = *reinterpret_cast<const bf16x8*>(
                Wb + (size_t)(wbase + mt * 16 + lr) * C_IN + ks * 32 + lg * 8);

    f32x4 acc[4][2];
#pragma unroll
    for (int mt = 0; mt < 4; mt++)
#pragma unroll
        for (int nt = 0; nt < 2; nt++) acc[mt][nt] = (f32x4)(0.0f);

    const unsigned short* gb = g + (size_t)b * N_OUT * C_IN;
#pragma unroll
    for (int nt = 0; nt < 2; nt++) {
        int n = n0 + nt * 16 + lr;
        const unsigned short* gr = gb + (size_t)((n < N_OUT) ? n : 0) * C_IN;
#pragma unroll
        for (int ks = 0; ks < 4; ks++) {
            bf16x8 bfr = *reinterpret_cast<const bf16x8*>(gr + ks * 32 + lg * 8);
#pragma unroll
            for (int mt = 0; mt < 4; mt++)
                acc[mt][nt] = __builtin_amdgcn_mfma_f32_16x16x32_bf16(afrag[mt][ks], bfr,
                                                                     acc[mt][nt], 0, 0, 0);
        }
    }

    float* ob = out + (size_t)b * C_OUT * N_OUT;
#pragma unroll
    for (int mt = 0; mt < 4; mt++) {
#pragma unroll
        for (int j = 0; j < 4; j++) {
            int o = wbase + mt * 16 + lg * 4 + j;
            float a = ss[o];
            float sh = ss[C_OUT + o];
#pragma unroll
            for (int nt = 0; nt < 2; nt++) {
                int n = n0 + nt * 16 + lr;
                if (n < N_OUT) ob[(size_t)o * N_OUT + n] = a * acc[mt][nt][j] + sh;
            }
        }
    }
}

// ---------------------------------------------------------------------------
extern "C" void kernel_launch(void* const* d_in, const int* in_sizes, int n_in,
                              void* d_out, int out_size, void* d_ws, size_t ws_size,
                              hipStream_t stream) {
    const float* x     = (const float*)d_in[0];
    const int*   idx   = (const int*)d_in[1];
    const float* W     = (const float*)d_in[2];
    const float* bias  = (const float*)d_in[3];
    const float* gamma = (const float*)d_in[4];
    const float* beta  = (const float*)d_in[5];
    float* out = (float*)d_out;

    const size_t xt_bytes = (size_t)B_ * N_IN * C_IN * sizeof(unsigned short);   // 41,945,088
    const size_t g_bytes  = (size_t)B_ * N_OUT * C_IN * sizeof(unsigned short);  // 10,487,808
    unsigned short* xT = (unsigned short*)d_ws;
    unsigned short* gg = (unsigned short*)((char*)d_ws + xt_bytes);
    unsigned short* Wb = (unsigned short*)((char*)d_ws + xt_bytes + g_bytes);
    // psum/psum2/ss overlay the xT region — xT is dead after k_gather, and the
    // stream serializes k_gather -> k_stats_gemm. (psum = 1284*512*4B = 2.63 MB)
    float* psum  = (float*)d_ws;
    float* psum2 = (float*)((char*)d_ws + 8u * 1024 * 1024);
    float* ss    = (float*)((char*)d_ws + 9u * 1024 * 1024);

    k_wconv<<<(C_OUT * C_IN) / 256, 256, 0, stream>>>(W, Wb);
    k_transpose<<<B_ * NB_I, 256, 0, stream>>>(x, xT);
    k_gather<<<B_ * NB_G, 256, 0, stream>>>(xT, idx, gg);
    k_stats_gemm<<<NBLK_STATS, 256, 0, stream>>>(gg, Wb, bias, psum);
    k_reduce<<<RED_BLKS, 256, 0, stream>>>(psum, psum2);
    k_finalize<<<1, C_OUT, 0, stream>>>(psum2, bias, gamma, beta, ss);
    k_final_gemm<<<B_ * NB_N2, 256, 0, stream>>>(gg, Wb, ss, out);
}